// Round 10
// baseline (155.185 us; speedup 1.0000x reference)
//
#include <hip/hip_runtime.h>
#include <math.h>

#define N_EL    16
#define N_NUC   4
#define N_FEATS 32
#define N_PAIRS 184
#define HIDDEN  64
#define TB      32           // batch elements per block
#define BLOCK   256
#define DLD     185          // dist LDS stride
#define H1LD    68           // h1 stride in kernel 2
#define TPW     23           // K-tiles (2 pairs each) per wave; 4*23*2 = 184
#define WS_H1_OFF (1 << 19)  // h1 buffer starts at 512 KB into d_ws (8 MB)

typedef int   intx8    __attribute__((ext_vector_type(8)));
typedef float floatx16 __attribute__((ext_vector_type(16)));

// triu_indices(16, 1)
__constant__ unsigned char c_I[120] = {
    0,0,0,0,0,0,0,0,0,0,0,0,0,0,0,
    1,1,1,1,1,1,1,1,1,1,1,1,1,1,
    2,2,2,2,2,2,2,2,2,2,2,2,2,
    3,3,3,3,3,3,3,3,3,3,3,3,
    4,4,4,4,4,4,4,4,4,4,4,
    5,5,5,5,5,5,5,5,5,5,
    6,6,6,6,6,6,6,6,6,
    7,7,7,7,7,7,7,7,
    8,8,8,8,8,8,8,
    9,9,9,9,9,9,
    10,10,10,10,10,
    11,11,11,11,
    12,12,12,
    13,13,
    14
};
__constant__ unsigned char c_J[120] = {
    1,2,3,4,5,6,7,8,9,10,11,12,13,14,15,
    2,3,4,5,6,7,8,9,10,11,12,13,14,15,
    3,4,5,6,7,8,9,10,11,12,13,14,15,
    4,5,6,7,8,9,10,11,12,13,14,15,
    5,6,7,8,9,10,11,12,13,14,15,
    6,7,8,9,10,11,12,13,14,15,
    7,8,9,10,11,12,13,14,15,
    8,9,10,11,12,13,14,15,
    9,10,11,12,13,14,15,
    10,11,12,13,14,15,
    11,12,13,14,15,
    12,13,14,15,
    13,14,15,
    14,15,
    15
};

__device__ __forceinline__ float ssp(float x) {
    float a = fabsf(x);
    return fmaxf(x, 0.0f) + log1pf(__expf(-a)) - 0.69314718056f;
}
__device__ __forceinline__ float redg(float v) {
    v += __shfl_xor(v, 1);
    v += __shfl_xor(v, 2);
    v += __shfl_xor(v, 4);
    return v;
}

// ---------------------------------------------------------------------------
// Prep (verified R14): W1 -> fp8 e4m3 (pre-scaled 2^6; MFMA applies 2^-6 via
// scale_b) in 32x32x64 B-fragment order.
// ---------------------------------------------------------------------------
__global__ __launch_bounds__(256)
void prep_w1_kernel(const float* __restrict__ W1, intx8* __restrict__ ws)
{
    __shared__ float w[2 * N_FEATS * HIDDEN];   // 16 KB: two pairs' rows
    const int t = blockIdx.x;
    const float* src = W1 + (size_t)(2 * t) * (N_FEATS * HIDDEN);
    for (int k = threadIdx.x; k < 2 * N_FEATS * HIDDEN; k += 256) w[k] = src[k];
    __syncthreads();

    const int tid = threadIdx.x;
    if (tid >= 128) return;
    const int lane = tid & 63;
    const int nh   = tid >> 6;
    const int lh   = lane >> 5;
    const int col  = nh * 32 + (lane & 31);
    const int fb   = lh * 16;
    intx8 frag;
#pragma unroll
    for (int r = 0; r < 8; ++r) {
        const int pair = r >> 2;
        const int fo   = fb + ((r & 3) << 2);
        const float v0 = 64.0f * w[(pair * N_FEATS + fo + 0) * 64 + col];
        const float v1 = 64.0f * w[(pair * N_FEATS + fo + 1) * 64 + col];
        const float v2 = 64.0f * w[(pair * N_FEATS + fo + 2) * 64 + col];
        const float v3 = 64.0f * w[(pair * N_FEATS + fo + 3) * 64 + col];
        int d = __builtin_amdgcn_cvt_pk_fp8_f32(v0, v1, 0, false);
        d     = __builtin_amdgcn_cvt_pk_fp8_f32(v2, v3, d, true);
        frag[r] = d;
    }
    ws[(size_t)(t * 2 + nh) * 64 + lane] = frag;
}

// ---------------------------------------------------------------------------
// Kernel 1 — GEMM + in-LDS reduction (R25). K-loop = R19/R24 verified path.
// R25: instead of dumping 4 x 8 KB raw partials per block (32 MB chip-wide),
// reduce across waves in LDS (red aliased over dead lds_dist): wave 0 plain-
// writes, barrier, waves 1-3 ds_add, barrier, then all threads apply b1+ssp
// and write finished h1 (8 KB/block, coalesced float4) -> 8 MB chip-wide.
// Tail no longer sums partials. Only the reduction moved here (R21's failure
// was moving the W2 layers too).
// ---------------------------------------------------------------------------
__global__ __launch_bounds__(BLOCK)
void wfnet_gemm(const float* __restrict__ rs,
                const float* __restrict__ coords,
                const intx8* __restrict__ ws,
                const float* __restrict__ b1,
                float* __restrict__ h1g)
{
    __shared__ float lds_rs[TB * N_EL * 3];   // 6 KB
    __shared__ float lds_dist[TB * DLD];      // 23.7 KB

    const int tid  = threadIdx.x;
    const int wave = tid >> 6;               // = kh
    const int lane = tid & 63;
    const int m    = lane & 31;
    const int lh   = lane >> 5;

    // ---- phase 1: stage rs ----
    {
        const float* rs_blk = rs + (size_t)blockIdx.x * (TB * N_EL * 3);
        for (int k = tid; k < TB * N_EL * 3; k += BLOCK) lds_rs[k] = rs_blk[k];
    }
    __syncthreads();

    // ---- phase 2: distances only ----
    {
        const int bl = tid >> 3, g = tid & 7;
        const float* myrs = lds_rs + bl * (N_EL * 3);
        float* dst = lds_dist + bl * DLD;
        for (int i = 0; i < 8; ++i) {
            const int p = g + 8 * i;
            const int e = p >> 2, n = p & 3;
            const float dx = myrs[e * 3 + 0] - coords[n * 3 + 0];
            const float dy = myrs[e * 3 + 1] - coords[n * 3 + 1];
            const float dz = myrs[e * 3 + 2] - coords[n * 3 + 2];
            dst[p] = sqrtf(dx * dx + dy * dy + dz * dz);
        }
        for (int i = 0; i < 15; ++i) {
            const int q  = g + 8 * i;
            const int ei = 3 * (int)c_I[q], ej = 3 * (int)c_J[q];
            const float dx = myrs[ei + 0] - myrs[ej + 0];
            const float dy = myrs[ei + 1] - myrs[ej + 1];
            const float dz = myrs[ei + 2] - myrs[ej + 2];
            dst[64 + q] = sqrtf(dx * dx + dy * dy + dz * dz);
        }
    }
    __syncthreads();

    // per-lane Gaussian constants for feats lh*16 .. lh*16+15
    // P1 = sqrt(8*log2 e)/sigma; byte = sat_u8(56.5 - (d*P1+P0)^2)
    const int f0 = lh * 16;
#define MKC(P, FF) float P##1, P##0; { \
    const float fq = (float)(FF) * (1.0f / 31.0f); \
    const float mu = 10.0f * fq * fq; \
    const float is = 7.0f / (1.0f + 10.0f * fq); \
    P##1 = is * 3.3972871404442143f; \
    P##0 = -mu * P##1; }
    MKC(F0_,  f0 + 0)  MKC(F1_,  f0 + 1)  MKC(F2_,  f0 + 2)  MKC(F3_,  f0 + 3)
    MKC(F4_,  f0 + 4)  MKC(F5_,  f0 + 5)  MKC(F6_,  f0 + 6)  MKC(F7_,  f0 + 7)
    MKC(F8_,  f0 + 8)  MKC(F9_,  f0 + 9)  MKC(F10_, f0 + 10) MKC(F11_, f0 + 11)
    MKC(F12_, f0 + 12) MKC(F13_, f0 + 13) MKC(F14_, f0 + 14) MKC(F15_, f0 + 15)
#undef MKC

    floatx16 accA = {};
    floatx16 accB = {};
    const intx8* wq = ws + ((size_t)(wave * TPW) * 128 + lane);
    const float* drow = lds_dist + m * DLD + wave * (2 * TPW);

    // z = 56.5 - t^2 (>=0 only near the Gaussian center; cvt clamps the rest)
#define XZ(dd, P) ({ const float t_ = fmaf(dd, P##1, P##0); fmaf(t_, -t_, 56.5f); })
#define PKD(dd, A, B, C, D) ({ \
    unsigned w_; \
    w_ = __builtin_amdgcn_cvt_pk_u8_f32(XZ(dd, A), 0, 0u); \
    w_ = __builtin_amdgcn_cvt_pk_u8_f32(XZ(dd, B), 1, w_); \
    w_ = __builtin_amdgcn_cvt_pk_u8_f32(XZ(dd, C), 2, w_); \
    w_ = __builtin_amdgcn_cvt_pk_u8_f32(XZ(dd, D), 3, w_); \
    (int)w_; })
#define MKA8(AV, dx0, dx1) \
    intx8 AV; { \
    AV[0] = PKD(dx0, F0_,  F1_,  F2_,  F3_);  \
    AV[1] = PKD(dx0, F4_,  F5_,  F6_,  F7_);  \
    AV[2] = PKD(dx0, F8_,  F9_,  F10_, F11_); \
    AV[3] = PKD(dx0, F12_, F13_, F14_, F15_); \
    AV[4] = PKD(dx1, F0_,  F1_,  F2_,  F3_);  \
    AV[5] = PKD(dx1, F4_,  F5_,  F6_,  F7_);  \
    AV[6] = PKD(dx1, F8_,  F9_,  F10_, F11_); \
    AV[7] = PKD(dx1, F12_, F13_, F14_, F15_); }
#define KROUND(AV, Q0, Q1) { \
    accA = __builtin_amdgcn_mfma_scale_f32_32x32x64_f8f6f4( \
               AV, Q0, accA, 0, 0, 0, 0x7F7F7F7F, 0, 0x79797979); \
    accB = __builtin_amdgcn_mfma_scale_f32_32x32x64_f8f6f4( \
               AV, Q1, accB, 0, 0, 0, 0x7F7F7F7F, 0, 0x79797979); }

    intx8 pA0 = wq[0],   pA1 = wq[64];
    intx8 pB0 = wq[128], pB1 = wq[192];
    float dA0 = drow[0], dA1 = drow[1];
    float dB0 = drow[2], dB1 = drow[3];

#pragma unroll 1
    for (int it = 0; it < 10; ++it) {
        const intx8* wn = wq + 256;
        const float eA0 = drow[4 * it + 4], eA1 = drow[4 * it + 5];
        const float eB0 = drow[4 * it + 6], eB1 = drow[4 * it + 7];

        { MKA8(av, dA0, dA1) KROUND(av, pA0, pA1) }
        pA0 = wn[0]; pA1 = wn[64];

        { MKA8(bv, dB0, dB1) KROUND(bv, pB0, pB1) }
        pB0 = wn[128]; pB1 = wn[192];

        wq = wn;
        dA0 = eA0; dA1 = eA1; dB0 = eB0; dB1 = eB1;
    }
    {
        const intx8* wn = wq + 256;
        const float eA0 = drow[44], eA1 = drow[45];
        { MKA8(av, dA0, dA1) KROUND(av, pA0, pA1) }
        pA0 = wn[0]; pA1 = wn[64];
        { MKA8(bv, dB0, dB1) KROUND(bv, pB0, pB1) }
        { MKA8(cv, eA0, eA1) KROUND(cv, pA0, pA1) }
    }
#undef KROUND
#undef MKA8
#undef PKD
#undef XZ

    // ---- R25 reduction: red aliased over lds_dist (dead after K-loop) ----
    float* red = lds_dist;                   // 2048 floats used
    __syncthreads();                         // all waves done reading lds_dist
    if (wave == 0) {
#pragma unroll
        for (int rg = 0; rg < 16; ++rg) {
            const int el = (rg & 3) + 8 * (rg >> 2) + 4 * lh;
            red[el * 64 + m]      = accA[rg];
            red[el * 64 + 32 + m] = accB[rg];
        }
    }
    __syncthreads();                         // wave 0's base values visible
    if (wave != 0) {
#pragma unroll
        for (int rg = 0; rg < 16; ++rg) {
            const int el = (rg & 3) + 8 * (rg >> 2) + 4 * lh;
            atomicAdd(&red[el * 64 + m],      accA[rg]);
            atomicAdd(&red[el * 64 + 32 + m], accB[rg]);
        }
    }
    __syncthreads();                         // sums final

    // ---- b1 + ssp -> h1 global (thread owns 8 contiguous: el = tid>>3,
    //      cols (tid&7)*8 .. +7; 2-way LDS read conflict = free) ----
    {
        const int c4 = (tid & 7) * 2;        // float4 index into b1
        const float4 ba = ((const float4*)b1)[c4];
        const float4 bb = ((const float4*)b1)[c4 + 1];
        const float* r = red + tid * 8;
        float4 h0, h1v;
        h0.x  = ssp(r[0] + ba.x); h0.y  = ssp(r[1] + ba.y);
        h0.z  = ssp(r[2] + ba.z); h0.w  = ssp(r[3] + ba.w);
        h1v.x = ssp(r[4] + bb.x); h1v.y = ssp(r[5] + bb.y);
        h1v.z = ssp(r[6] + bb.z); h1v.w = ssp(r[7] + bb.w);
        float4* dst = (float4*)(h1g + (size_t)blockIdx.x * 2048 + tid * 8);
        dst[0] = h0; dst[1] = h1v;
    }
}

// ---------------------------------------------------------------------------
// Kernel 2 — tail: load finished h1 (8 KB/block) -> LDS, layers 2/3 + asy +
// output. W2 staged in LDS (R17, verified).
// ---------------------------------------------------------------------------
__global__ __launch_bounds__(BLOCK)
void wfnet_tail(const float* __restrict__ rs,
                const float* __restrict__ coords,
                const float* __restrict__ charges,
                const float* __restrict__ h1g,
                const float* __restrict__ W2,
                const float* __restrict__ b2,
                const float* __restrict__ W3,
                const float* __restrict__ b3,
                float* __restrict__ out)
{
    __shared__ float lds_rs[TB * N_EL * 3];   // 6 KB
    __shared__ float lds_h1[TB * H1LD];       // 8.7 KB
    __shared__ float lds_w2[HIDDEN * HIDDEN]; // 16 KB

    const int tid = threadIdx.x;
    const int el  = tid >> 3;                // 0..31
    const int g   = tid & 7;
    const int b   = blockIdx.x * TB + el;

    // stage rs for asy
    {
        const float* rs_blk = rs + (size_t)blockIdx.x * (TB * N_EL * 3);
        for (int k = tid; k < TB * N_EL * 3; k += BLOCK) lds_rs[k] = rs_blk[k];
    }
    // stage W2 (4 float4 per thread)
    {
        float4* dst = (float4*)lds_w2;
        const float4* src = (const float4*)W2;
#pragma unroll
        for (int i = 0; i < 4; ++i) dst[tid + 256 * i] = src[tid + 256 * i];
    }
    // stage h1: thread loads its 8 contiguous floats (coalesced), writes
    // LDS at stride H1LD=68 (16B-aligned: el*272 + c0*4)
    {
        const float4* src = (const float4*)(h1g + (size_t)blockIdx.x * 2048 + tid * 8);
        const float4 a = src[0];
        const float4 bq = src[1];
        float4* d = (float4*)(lds_h1 + el * H1LD + g * 8);
        d[0] = a; d[1] = bq;
    }

    // asy partial: this thread's 8 el-nuc pairs (needs only lds_rs)
    float asy = 0.0f;
    __syncthreads();   // rs + W2 + h1 staged
    {
        const float* myrs = lds_rs + el * (N_EL * 3);
        const float4 ch = *(const float4*)charges;
#pragma unroll
        for (int i = 0; i < 8; ++i) {
            const int p = g + 8 * i;
            const int e = p >> 2, n = p & 3;
            const float dx = myrs[e * 3 + 0] - coords[n * 3 + 0];
            const float dy = myrs[e * 3 + 1] - coords[n * 3 + 1];
            const float dz = myrs[e * 3 + 2] - coords[n * 3 + 2];
            const float d = sqrtf(dx * dx + dy * dy + dz * dz);
            const float Z = (n < 2) ? ((n == 0) ? ch.x : ch.y)
                                    : ((n == 2) ? ch.z : ch.w);
            asy += (Z * d + d * d) / (1.0f + d);   // decay = sqrt(2*0.5) = 1
        }
    }
    asy = redg(asy);

    // layers 2/3 (W2 from LDS)
    const float4* __restrict__ W2v = (const float4*)lds_w2;
    const float4* __restrict__ b2v = (const float4*)b2;
    const int wbi = g * 2;
    const float4 b2a = b2v[wbi], b2b = b2v[wbi + 1];
    float s0 = b2a.x, s1 = b2a.y, s2 = b2a.z, s3 = b2a.w;
    float s4 = b2b.x, s5 = b2b.y, s6 = b2b.z, s7 = b2b.w;

    const float* __restrict__ h1row = lds_h1 + el * H1LD;
    for (int k = 0; k < HIDDEN; ++k) {
        const float hk  = h1row[k];
        const float4 wa = W2v[k * 16 + wbi];
        const float4 wb = W2v[k * 16 + wbi + 1];
        s0 = fmaf(hk, wa.x, s0); s1 = fmaf(hk, wa.y, s1);
        s2 = fmaf(hk, wa.z, s2); s3 = fmaf(hk, wa.w, s3);
        s4 = fmaf(hk, wb.x, s4); s5 = fmaf(hk, wb.y, s5);
        s6 = fmaf(hk, wb.z, s6); s7 = fmaf(hk, wb.w, s7);
    }

    const float4* __restrict__ W3v = (const float4*)W3;
    const float4 w3a = W3v[wbi], w3b = W3v[wbi + 1];
    float part = ssp(s0) * w3a.x + ssp(s1) * w3a.y
               + ssp(s2) * w3a.z + ssp(s3) * w3a.w
               + ssp(s4) * w3b.x + ssp(s5) * w3b.y
               + ssp(s6) * w3b.z + ssp(s7) * w3b.w;
    part = redg(part);

    if (g == 0) {
        const float ys = part + b3[0];
        out[b] = __expf(ys) * __expf(-asy);
    }
}

extern "C" void kernel_launch(void* const* d_in, const int* in_sizes, int n_in,
                              void* d_out, int out_size, void* d_ws, size_t ws_size,
                              hipStream_t stream) {
    const float* rs      = (const float*)d_in[0];
    const float* coords  = (const float*)d_in[1];
    const float* charges = (const float*)d_in[2];
    const float* W1      = (const float*)d_in[3];
    const float* b1      = (const float*)d_in[4];
    const float* W2      = (const float*)d_in[5];
    const float* b2      = (const float*)d_in[6];
    const float* W3      = (const float*)d_in[7];
    const float* b3      = (const float*)d_in[8];
    float* out = (float*)d_out;

    const int batch = in_sizes[0] / (N_EL * 3);   // 32768
    intx8* w1f8     = (intx8*)d_ws;               // 368 KB fp8 W1
    float* h1g      = (float*)((char*)d_ws + WS_H1_OFF);  // 8 MB finished h1

    prep_w1_kernel<<<N_PAIRS / 2, 256, 0, stream>>>(W1, w1f8);
    wfnet_gemm<<<batch / TB, BLOCK, 0, stream>>>(rs, coords, w1f8, b1, h1g);
    wfnet_tail<<<batch / TB, BLOCK, 0, stream>>>(rs, coords, charges, h1g,
                                                 W2, b2, W3, b3, out);
}

// Round 11
// 137.575 us; speedup vs baseline: 1.1280x; 1.1280x over previous
//
#include <hip/hip_runtime.h>
#include <math.h>

#define N_EL    16
#define N_NUC   4
#define N_FEATS 32
#define N_PAIRS 184
#define HIDDEN  64
#define TB      32           // batch elements per block
#define BLOCK   512          // R26: 8 waves per block, half K-range each
#define DLD     185          // dist LDS stride
#define H1LD    68           // h1 stride in kernel 2
#define TPW     23           // K-tiles per original wave quarter
#define WS_PART_OFF (1 << 19)   // partials start at 512 KB into d_ws

typedef int   intx8    __attribute__((ext_vector_type(8)));
typedef float floatx16 __attribute__((ext_vector_type(16)));

// triu_indices(16, 1)
__constant__ unsigned char c_I[120] = {
    0,0,0,0,0,0,0,0,0,0,0,0,0,0,0,
    1,1,1,1,1,1,1,1,1,1,1,1,1,1,
    2,2,2,2,2,2,2,2,2,2,2,2,2,
    3,3,3,3,3,3,3,3,3,3,3,3,
    4,4,4,4,4,4,4,4,4,4,4,
    5,5,5,5,5,5,5,5,5,5,
    6,6,6,6,6,6,6,6,6,
    7,7,7,7,7,7,7,7,
    8,8,8,8,8,8,8,
    9,9,9,9,9,9,
    10,10,10,10,10,
    11,11,11,11,
    12,12,12,
    13,13,
    14
};
__constant__ unsigned char c_J[120] = {
    1,2,3,4,5,6,7,8,9,10,11,12,13,14,15,
    2,3,4,5,6,7,8,9,10,11,12,13,14,15,
    3,4,5,6,7,8,9,10,11,12,13,14,15,
    4,5,6,7,8,9,10,11,12,13,14,15,
    5,6,7,8,9,10,11,12,13,14,15,
    6,7,8,9,10,11,12,13,14,15,
    7,8,9,10,11,12,13,14,15,
    8,9,10,11,12,13,14,15,
    9,10,11,12,13,14,15,
    10,11,12,13,14,15,
    11,12,13,14,15,
    12,13,14,15,
    13,14,15,
    14,15,
    15
};

__device__ __forceinline__ float ssp(float x) {
    float a = fabsf(x);
    return fmaxf(x, 0.0f) + log1pf(__expf(-a)) - 0.69314718056f;
}
__device__ __forceinline__ float redg(float v) {
    v += __shfl_xor(v, 1);
    v += __shfl_xor(v, 2);
    v += __shfl_xor(v, 4);
    return v;
}

// ---------------------------------------------------------------------------
// Prep (verified R14): W1 -> fp8 e4m3 (pre-scaled 2^6; MFMA applies 2^-6 via
// scale_b) in 32x32x64 B-fragment order.
// ---------------------------------------------------------------------------
__global__ __launch_bounds__(256)
void prep_w1_kernel(const float* __restrict__ W1, intx8* __restrict__ ws)
{
    __shared__ float w[2 * N_FEATS * HIDDEN];   // 16 KB: two pairs' rows
    const int t = blockIdx.x;
    const float* src = W1 + (size_t)(2 * t) * (N_FEATS * HIDDEN);
    for (int k = threadIdx.x; k < 2 * N_FEATS * HIDDEN; k += 256) w[k] = src[k];
    __syncthreads();

    const int tid = threadIdx.x;
    if (tid >= 128) return;
    const int lane = tid & 63;
    const int nh   = tid >> 6;
    const int lh   = lane >> 5;
    const int col  = nh * 32 + (lane & 31);
    const int fb   = lh * 16;
    intx8 frag;
#pragma unroll
    for (int r = 0; r < 8; ++r) {
        const int pair = r >> 2;
        const int fo   = fb + ((r & 3) << 2);
        const float v0 = 64.0f * w[(pair * N_FEATS + fo + 0) * 64 + col];
        const float v1 = 64.0f * w[(pair * N_FEATS + fo + 1) * 64 + col];
        const float v2 = 64.0f * w[(pair * N_FEATS + fo + 2) * 64 + col];
        const float v3 = 64.0f * w[(pair * N_FEATS + fo + 3) * 64 + col];
        int d = __builtin_amdgcn_cvt_pk_fp8_f32(v0, v1, 0, false);
        d     = __builtin_amdgcn_cvt_pk_fp8_f32(v2, v3, d, true);
        frag[r] = d;
    }
    ws[(size_t)(t * 2 + nh) * 64 + lane] = frag;
}

// ---------------------------------------------------------------------------
// Kernel 1 — GEMM. R26: per-wave serial-time test. Grid unchanged (1024
// blocks = one resident generation, so wall == per-wave serial time), but
// 8 waves/block: wave (w4, half) = (wave&3, wave>>2) handles half of the
// original quarter — tiles [23*w4 + 12*half, +12) for half=0, +11) for
// half=1 (5 double rounds + 1 single full tile). Feature path = R19
// verified (e4m3 direct byte, builtin cvt_pk_u8). Each wave dumps its own
// 32x64 partial (8 per block); tail sums 8.
// ---------------------------------------------------------------------------
__global__ __launch_bounds__(BLOCK)
void wfnet_gemm(const float* __restrict__ rs,
                const float* __restrict__ coords,
                const intx8* __restrict__ ws,
                float* __restrict__ partials)
{
    __shared__ float lds_rs[TB * N_EL * 3];   // 6 KB
    __shared__ float lds_dist[TB * DLD];      // 23.7 KB

    const int tid  = threadIdx.x;
    const int wave = tid >> 6;               // 0..7
    const int lane = tid & 63;
    const int m    = lane & 31;
    const int lh   = lane >> 5;
    const int w4   = wave & 3;               // K quarter
    const int half = wave >> 2;              // half within quarter

    // ---- phase 1: stage rs ----
    {
        const float* rs_blk = rs + (size_t)blockIdx.x * (TB * N_EL * 3);
        for (int k = tid; k < TB * N_EL * 3; k += BLOCK) lds_rs[k] = rs_blk[k];
    }
    __syncthreads();

    // ---- phase 2: distances (16 threads per batch row) ----
    {
        const int bl = tid >> 4, g = tid & 15;
        const float* myrs = lds_rs + bl * (N_EL * 3);
        float* dst = lds_dist + bl * DLD;
#pragma unroll
        for (int i = 0; i < 4; ++i) {
            const int p = g + 16 * i;
            const int e = p >> 2, n = p & 3;
            const float dx = myrs[e * 3 + 0] - coords[n * 3 + 0];
            const float dy = myrs[e * 3 + 1] - coords[n * 3 + 1];
            const float dz = myrs[e * 3 + 2] - coords[n * 3 + 2];
            dst[p] = sqrtf(dx * dx + dy * dy + dz * dz);
        }
#pragma unroll
        for (int i = 0; i < 8; ++i) {
            const int q = g + 16 * i;
            if (q < 120) {
                const int ei = 3 * (int)c_I[q], ej = 3 * (int)c_J[q];
                const float dx = myrs[ei + 0] - myrs[ej + 0];
                const float dy = myrs[ei + 1] - myrs[ej + 1];
                const float dz = myrs[ei + 2] - myrs[ej + 2];
                dst[64 + q] = sqrtf(dx * dx + dy * dy + dz * dz);
            }
        }
    }
    __syncthreads();

    // per-lane Gaussian constants for feats lh*16 .. lh*16+15
    // P1 = sqrt(8*log2 e)/sigma; byte = sat_u8(56.5 - (d*P1+P0)^2)
    const int f0 = lh * 16;
#define MKC(P, FF) float P##1, P##0; { \
    const float fq = (float)(FF) * (1.0f / 31.0f); \
    const float mu = 10.0f * fq * fq; \
    const float is = 7.0f / (1.0f + 10.0f * fq); \
    P##1 = is * 3.3972871404442143f; \
    P##0 = -mu * P##1; }
    MKC(F0_,  f0 + 0)  MKC(F1_,  f0 + 1)  MKC(F2_,  f0 + 2)  MKC(F3_,  f0 + 3)
    MKC(F4_,  f0 + 4)  MKC(F5_,  f0 + 5)  MKC(F6_,  f0 + 6)  MKC(F7_,  f0 + 7)
    MKC(F8_,  f0 + 8)  MKC(F9_,  f0 + 9)  MKC(F10_, f0 + 10) MKC(F11_, f0 + 11)
    MKC(F12_, f0 + 12) MKC(F13_, f0 + 13) MKC(F14_, f0 + 14) MKC(F15_, f0 + 15)
#undef MKC

    floatx16 accA = {};
    floatx16 accB = {};
    // tiles [23*w4 + 12*half, ...): 12 tiles (half=0) or 11 (half=1)
    const intx8* wq = ws + ((size_t)(23 * w4 + 12 * half) * 128 + lane);
    const float* drow = lds_dist + m * DLD + 46 * w4 + 24 * half;
    const int nd = 6 - half;                 // double rounds

#define XZ(dd, P) ({ const float t_ = fmaf(dd, P##1, P##0); fmaf(t_, -t_, 56.5f); })
#define PKD(dd, A, B, C, D) ({ \
    unsigned w_; \
    w_ = __builtin_amdgcn_cvt_pk_u8_f32(XZ(dd, A), 0, 0u); \
    w_ = __builtin_amdgcn_cvt_pk_u8_f32(XZ(dd, B), 1, w_); \
    w_ = __builtin_amdgcn_cvt_pk_u8_f32(XZ(dd, C), 2, w_); \
    w_ = __builtin_amdgcn_cvt_pk_u8_f32(XZ(dd, D), 3, w_); \
    (int)w_; })
#define MKA8(AV, dx0, dx1) \
    intx8 AV; { \
    AV[0] = PKD(dx0, F0_,  F1_,  F2_,  F3_);  \
    AV[1] = PKD(dx0, F4_,  F5_,  F6_,  F7_);  \
    AV[2] = PKD(dx0, F8_,  F9_,  F10_, F11_); \
    AV[3] = PKD(dx0, F12_, F13_, F14_, F15_); \
    AV[4] = PKD(dx1, F0_,  F1_,  F2_,  F3_);  \
    AV[5] = PKD(dx1, F4_,  F5_,  F6_,  F7_);  \
    AV[6] = PKD(dx1, F8_,  F9_,  F10_, F11_); \
    AV[7] = PKD(dx1, F12_, F13_, F14_, F15_); }
#define KROUND(AV, Q0, Q1) { \
    accA = __builtin_amdgcn_mfma_scale_f32_32x32x64_f8f6f4( \
               AV, Q0, accA, 0, 0, 0, 0x7F7F7F7F, 0, 0x79797979); \
    accB = __builtin_amdgcn_mfma_scale_f32_32x32x64_f8f6f4( \
               AV, Q1, accB, 0, 0, 0, 0x7F7F7F7F, 0, 0x79797979); }

#pragma unroll 1
    for (int it = 0; it < nd; ++it) {
        const intx8 a0 = wq[0],   a1 = wq[64];
        const intx8 b0 = wq[128], b1 = wq[192];
        const float d0 = drow[4 * it + 0], d1 = drow[4 * it + 1];
        const float d2 = drow[4 * it + 2], d3 = drow[4 * it + 3];
        { MKA8(av, d0, d1) KROUND(av, a0, a1) }
        { MKA8(bv, d2, d3) KROUND(bv, b0, b1) }
        wq += 256;
    }
    if (half) {                              // tile 22 of the quarter (full)
        const intx8 a0 = wq[0], a1 = wq[64];
        const float d0 = drow[20], d1 = drow[21];
        { MKA8(cv, d0, d1) KROUND(cv, a0, a1) }
    }
#undef KROUND
#undef MKA8
#undef PKD
#undef XZ

    // ---- dump raw partial to global, no barrier. C/D layout:
    //      col = lane&31 (+32 for B), row el = (rg&3) + 8*(rg>>2) + 4*lh ----
    float* pdst = partials + ((size_t)blockIdx.x * 8 + wave) * 2048;
#pragma unroll
    for (int rg = 0; rg < 16; ++rg) {
        const int el = (rg & 3) + 8 * (rg >> 2) + 4 * lh;
        pdst[el * 64 + m]      = accA[rg];
        pdst[el * 64 + 32 + m] = accB[rg];
    }
}

// ---------------------------------------------------------------------------
// Kernel 2 — tail: sum 8 partials + b1 + ssp -> h1 (LDS) -> layers 2/3 +
// asy + output. W2 staged in LDS (R17, verified).
// ---------------------------------------------------------------------------
__global__ __launch_bounds__(256)
void wfnet_tail(const float* __restrict__ rs,
                const float* __restrict__ coords,
                const float* __restrict__ charges,
                const float* __restrict__ partials,
                const float* __restrict__ b1,
                const float* __restrict__ W2,
                const float* __restrict__ b2,
                const float* __restrict__ W3,
                const float* __restrict__ b3,
                float* __restrict__ out)
{
    __shared__ float lds_rs[TB * N_EL * 3];   // 6 KB
    __shared__ float lds_h1[TB * H1LD];       // 8.7 KB
    __shared__ float lds_w2[HIDDEN * HIDDEN]; // 16 KB

    const int tid = threadIdx.x;
    const int el  = tid >> 3;                // 0..31
    const int g   = tid & 7;
    const int b   = blockIdx.x * TB + el;

    // stage rs for asy
    {
        const float* rs_blk = rs + (size_t)blockIdx.x * (TB * N_EL * 3);
        for (int k = tid; k < TB * N_EL * 3; k += 256) lds_rs[k] = rs_blk[k];
    }
    // stage W2 (4 float4 per thread)
    {
        float4* dst = (float4*)lds_w2;
        const float4* src = (const float4*)W2;
#pragma unroll
        for (int i = 0; i < 4; ++i) dst[tid + 256 * i] = src[tid + 256 * i];
    }

    // sum 8 wave-partials for (el, cols g*8..g*8+7), + b1, ssp -> LDS h1
    {
        const float* pb = partials + (size_t)blockIdx.x * 16384 + el * 64 + g * 8;
        float4 s0 = {0.f, 0.f, 0.f, 0.f}, s1 = {0.f, 0.f, 0.f, 0.f};
#pragma unroll
        for (int wv = 0; wv < 8; ++wv) {
            const float4 a = ((const float4*)(pb + wv * 2048))[0];
            const float4 c = ((const float4*)(pb + wv * 2048))[1];
            s0.x += a.x; s0.y += a.y; s0.z += a.z; s0.w += a.w;
            s1.x += c.x; s1.y += c.y; s1.z += c.z; s1.w += c.w;
        }
        const float4 ba = ((const float4*)(b1 + g * 8))[0];
        const float4 bb = ((const float4*)(b1 + g * 8))[1];
        float* h1w = lds_h1 + el * H1LD + g * 8;
        h1w[0] = ssp(s0.x + ba.x);
        h1w[1] = ssp(s0.y + ba.y);
        h1w[2] = ssp(s0.z + ba.z);
        h1w[3] = ssp(s0.w + ba.w);
        h1w[4] = ssp(s1.x + bb.x);
        h1w[5] = ssp(s1.y + bb.y);
        h1w[6] = ssp(s1.z + bb.z);
        h1w[7] = ssp(s1.w + bb.w);
    }

    // asy partial: this thread's 8 el-nuc pairs (needs only lds_rs)
    float asy = 0.0f;
    __syncthreads();   // rs + W2 staged AND h1 visible
    {
        const float* myrs = lds_rs + el * (N_EL * 3);
        const float4 ch = *(const float4*)charges;
#pragma unroll
        for (int i = 0; i < 8; ++i) {
            const int p = g + 8 * i;
            const int e = p >> 2, n = p & 3;
            const float dx = myrs[e * 3 + 0] - coords[n * 3 + 0];
            const float dy = myrs[e * 3 + 1] - coords[n * 3 + 1];
            const float dz = myrs[e * 3 + 2] - coords[n * 3 + 2];
            const float d = sqrtf(dx * dx + dy * dy + dz * dz);
            const float Z = (n < 2) ? ((n == 0) ? ch.x : ch.y)
                                    : ((n == 2) ? ch.z : ch.w);
            asy += (Z * d + d * d) / (1.0f + d);   // decay = sqrt(2*0.5) = 1
        }
    }
    asy = redg(asy);

    // layers 2/3 (W2 from LDS)
    const float4* __restrict__ W2v = (const float4*)lds_w2;
    const float4* __restrict__ b2v = (const float4*)b2;
    const int wbi = g * 2;
    const float4 b2a = b2v[wbi], b2b = b2v[wbi + 1];
    float s0 = b2a.x, s1 = b2a.y, s2 = b2a.z, s3 = b2a.w;
    float s4 = b2b.x, s5 = b2b.y, s6 = b2b.z, s7 = b2b.w;

    const float* __restrict__ h1row = lds_h1 + el * H1LD;
    for (int k = 0; k < HIDDEN; ++k) {
        const float hk  = h1row[k];
        const float4 wa = W2v[k * 16 + wbi];
        const float4 wb = W2v[k * 16 + wbi + 1];
        s0 = fmaf(hk, wa.x, s0); s1 = fmaf(hk, wa.y, s1);
        s2 = fmaf(hk, wa.z, s2); s3 = fmaf(hk, wa.w, s3);
        s4 = fmaf(hk, wb.x, s4); s5 = fmaf(hk, wb.y, s5);
        s6 = fmaf(hk, wb.z, s6); s7 = fmaf(hk, wb.w, s7);
    }

    const float4* __restrict__ W3v = (const float4*)W3;
    const float4 w3a = W3v[wbi], w3b = W3v[wbi + 1];
    float part = ssp(s0) * w3a.x + ssp(s1) * w3a.y
               + ssp(s2) * w3a.z + ssp(s3) * w3a.w
               + ssp(s4) * w3b.x + ssp(s5) * w3b.y
               + ssp(s6) * w3b.z + ssp(s7) * w3b.w;
    part = redg(part);

    if (g == 0) {
        const float ys = part + b3[0];
        out[b] = __expf(ys) * __expf(-asy);
    }
}

extern "C" void kernel_launch(void* const* d_in, const int* in_sizes, int n_in,
                              void* d_out, int out_size, void* d_ws, size_t ws_size,
                              hipStream_t stream) {
    const float* rs      = (const float*)d_in[0];
    const float* coords  = (const float*)d_in[1];
    const float* charges = (const float*)d_in[2];
    const float* W1      = (const float*)d_in[3];
    const float* b1      = (const float*)d_in[4];
    const float* W2      = (const float*)d_in[5];
    const float* b2      = (const float*)d_in[6];
    const float* W3      = (const float*)d_in[7];
    const float* b3      = (const float*)d_in[8];
    float* out = (float*)d_out;

    const int batch = in_sizes[0] / (N_EL * 3);   // 32768
    intx8* w1f8     = (intx8*)d_ws;               // 368 KB fp8 W1
    float* partials = (float*)((char*)d_ws + WS_PART_OFF);  // 64 MB

    prep_w1_kernel<<<N_PAIRS / 2, 256, 0, stream>>>(W1, w1f8);
    wfnet_gemm<<<batch / TB, BLOCK, 0, stream>>>(rs, coords, w1f8, partials);
    wfnet_tail<<<batch / TB, 256, 0, stream>>>(rs, coords, charges, partials,
                                               b1, W2, b2, W3, b3, out);
}

// Round 12
// 128.211 us; speedup vs baseline: 1.2104x; 1.0730x over previous
//
#include <hip/hip_runtime.h>
#include <math.h>

#define N_EL    16
#define N_NUC   4
#define N_FEATS 32
#define N_PAIRS 184
#define HIDDEN  64
#define TB      32           // batch elements per block
#define BLOCK   256
#define DLD     185          // dist LDS stride
#define H1LD    68           // h1 stride in kernel 2
#define TPW     23           // K-tiles (2 pairs each) per wave; 4*23*2 = 184
#define WS_PART_OFF (1 << 19)   // partials start at 512 KB into d_ws

typedef int   intx8    __attribute__((ext_vector_type(8)));
typedef float floatx16 __attribute__((ext_vector_type(16)));

// triu_indices(16, 1)
__constant__ unsigned char c_I[120] = {
    0,0,0,0,0,0,0,0,0,0,0,0,0,0,0,
    1,1,1,1,1,1,1,1,1,1,1,1,1,1,
    2,2,2,2,2,2,2,2,2,2,2,2,2,
    3,3,3,3,3,3,3,3,3,3,3,3,
    4,4,4,4,4,4,4,4,4,4,4,
    5,5,5,5,5,5,5,5,5,5,
    6,6,6,6,6,6,6,6,6,
    7,7,7,7,7,7,7,7,
    8,8,8,8,8,8,8,
    9,9,9,9,9,9,
    10,10,10,10,10,
    11,11,11,11,
    12,12,12,
    13,13,
    14
};
__constant__ unsigned char c_J[120] = {
    1,2,3,4,5,6,7,8,9,10,11,12,13,14,15,
    2,3,4,5,6,7,8,9,10,11,12,13,14,15,
    3,4,5,6,7,8,9,10,11,12,13,14,15,
    4,5,6,7,8,9,10,11,12,13,14,15,
    5,6,7,8,9,10,11,12,13,14,15,
    6,7,8,9,10,11,12,13,14,15,
    7,8,9,10,11,12,13,14,15,
    8,9,10,11,12,13,14,15,
    9,10,11,12,13,14,15,
    10,11,12,13,14,15,
    11,12,13,14,15,
    12,13,14,15,
    13,14,15,
    14,15,
    15
};

__device__ __forceinline__ float ssp(float x) {
    float a = fabsf(x);
    return fmaxf(x, 0.0f) + log1pf(__expf(-a)) - 0.69314718056f;
}
__device__ __forceinline__ float redg(float v) {
    v += __shfl_xor(v, 1);
    v += __shfl_xor(v, 2);
    v += __shfl_xor(v, 4);
    return v;
}

// ---------------------------------------------------------------------------
// Prep (verified R14): W1 -> fp8 e4m3 (pre-scaled 2^6; MFMA applies 2^-6 via
// scale_b) in 32x32x64 B-fragment order.
// ---------------------------------------------------------------------------
__global__ __launch_bounds__(256)
void prep_w1_kernel(const float* __restrict__ W1, intx8* __restrict__ ws)
{
    __shared__ float w[2 * N_FEATS * HIDDEN];   // 16 KB: two pairs' rows
    const int t = blockIdx.x;
    const float* src = W1 + (size_t)(2 * t) * (N_FEATS * HIDDEN);
    for (int k = threadIdx.x; k < 2 * N_FEATS * HIDDEN; k += 256) w[k] = src[k];
    __syncthreads();

    const int tid = threadIdx.x;
    if (tid >= 128) return;
    const int lane = tid & 63;
    const int nh   = tid >> 6;
    const int lh   = lane >> 5;
    const int col  = nh * 32 + (lane & 31);
    const int fb   = lh * 16;
    intx8 frag;
#pragma unroll
    for (int r = 0; r < 8; ++r) {
        const int pair = r >> 2;
        const int fo   = fb + ((r & 3) << 2);
        const float v0 = 64.0f * w[(pair * N_FEATS + fo + 0) * 64 + col];
        const float v1 = 64.0f * w[(pair * N_FEATS + fo + 1) * 64 + col];
        const float v2 = 64.0f * w[(pair * N_FEATS + fo + 2) * 64 + col];
        const float v3 = 64.0f * w[(pair * N_FEATS + fo + 3) * 64 + col];
        int d = __builtin_amdgcn_cvt_pk_fp8_f32(v0, v1, 0, false);
        d     = __builtin_amdgcn_cvt_pk_fp8_f32(v2, v3, d, true);
        frag[r] = d;
    }
    ws[(size_t)(t * 2 + nh) * 64 + lane] = frag;
}

// ---------------------------------------------------------------------------
// Kernel 1 — GEMM (R19, session-best verified: 129.1 us total, absmax 0).
// Feature path: byte = e4m3 bit pattern sat_u8(56.5 - t'^2) with
// t' = sqrt(8 log2 e)(d-mu)/sigma; 3 schedulable VALU/feature via builtin
// cvt_pk_u8. Session post-mortem: gemm wall ~45 us is invariant to VALU
// count, load depth, occupancy, I$ footprint, and per-wave K length —
// unattributed CU-level stall; all structural deviations measured worse.
// ---------------------------------------------------------------------------
__global__ __launch_bounds__(BLOCK)
void wfnet_gemm(const float* __restrict__ rs,
                const float* __restrict__ coords,
                const intx8* __restrict__ ws,
                float* __restrict__ partials)
{
    __shared__ float lds_rs[TB * N_EL * 3];   // 6 KB
    __shared__ float lds_dist[TB * DLD];      // 23.7 KB

    const int tid  = threadIdx.x;
    const int wave = tid >> 6;               // = kh
    const int lane = tid & 63;
    const int m    = lane & 31;
    const int lh   = lane >> 5;

    // ---- phase 1: stage rs ----
    {
        const float* rs_blk = rs + (size_t)blockIdx.x * (TB * N_EL * 3);
        for (int k = tid; k < TB * N_EL * 3; k += BLOCK) lds_rs[k] = rs_blk[k];
    }
    __syncthreads();

    // ---- phase 2: distances only ----
    {
        const int bl = tid >> 3, g = tid & 7;
        const float* myrs = lds_rs + bl * (N_EL * 3);
        float* dst = lds_dist + bl * DLD;
        for (int i = 0; i < 8; ++i) {
            const int p = g + 8 * i;
            const int e = p >> 2, n = p & 3;
            const float dx = myrs[e * 3 + 0] - coords[n * 3 + 0];
            const float dy = myrs[e * 3 + 1] - coords[n * 3 + 1];
            const float dz = myrs[e * 3 + 2] - coords[n * 3 + 2];
            dst[p] = sqrtf(dx * dx + dy * dy + dz * dz);
        }
        for (int i = 0; i < 15; ++i) {
            const int q  = g + 8 * i;
            const int ei = 3 * (int)c_I[q], ej = 3 * (int)c_J[q];
            const float dx = myrs[ei + 0] - myrs[ej + 0];
            const float dy = myrs[ei + 1] - myrs[ej + 1];
            const float dz = myrs[ei + 2] - myrs[ej + 2];
            dst[64 + q] = sqrtf(dx * dx + dy * dy + dz * dz);
        }
    }
    __syncthreads();

    // per-lane Gaussian constants for feats lh*16 .. lh*16+15
    // P1 = sqrt(8*log2 e)/sigma; byte = sat_u8(56.5 - (d*P1+P0)^2)
    const int f0 = lh * 16;
#define MKC(P, FF) float P##1, P##0; { \
    const float fq = (float)(FF) * (1.0f / 31.0f); \
    const float mu = 10.0f * fq * fq; \
    const float is = 7.0f / (1.0f + 10.0f * fq); \
    P##1 = is * 3.3972871404442143f; \
    P##0 = -mu * P##1; }
    MKC(F0_,  f0 + 0)  MKC(F1_,  f0 + 1)  MKC(F2_,  f0 + 2)  MKC(F3_,  f0 + 3)
    MKC(F4_,  f0 + 4)  MKC(F5_,  f0 + 5)  MKC(F6_,  f0 + 6)  MKC(F7_,  f0 + 7)
    MKC(F8_,  f0 + 8)  MKC(F9_,  f0 + 9)  MKC(F10_, f0 + 10) MKC(F11_, f0 + 11)
    MKC(F12_, f0 + 12) MKC(F13_, f0 + 13) MKC(F14_, f0 + 14) MKC(F15_, f0 + 15)
#undef MKC

    floatx16 accA = {};
    floatx16 accB = {};
    const intx8* wq = ws + ((size_t)(wave * TPW) * 128 + lane);
    const float* drow = lds_dist + m * DLD + wave * (2 * TPW);

    // z = 56.5 - t^2 (>=0 only near the Gaussian center; cvt clamps the rest)
#define XZ(dd, P) ({ const float t_ = fmaf(dd, P##1, P##0); fmaf(t_, -t_, 56.5f); })
#define PKD(dd, A, B, C, D) ({ \
    unsigned w_; \
    w_ = __builtin_amdgcn_cvt_pk_u8_f32(XZ(dd, A), 0, 0u); \
    w_ = __builtin_amdgcn_cvt_pk_u8_f32(XZ(dd, B), 1, w_); \
    w_ = __builtin_amdgcn_cvt_pk_u8_f32(XZ(dd, C), 2, w_); \
    w_ = __builtin_amdgcn_cvt_pk_u8_f32(XZ(dd, D), 3, w_); \
    (int)w_; })
#define MKA8(AV, dx0, dx1) \
    intx8 AV; { \
    AV[0] = PKD(dx0, F0_,  F1_,  F2_,  F3_);  \
    AV[1] = PKD(dx0, F4_,  F5_,  F6_,  F7_);  \
    AV[2] = PKD(dx0, F8_,  F9_,  F10_, F11_); \
    AV[3] = PKD(dx0, F12_, F13_, F14_, F15_); \
    AV[4] = PKD(dx1, F0_,  F1_,  F2_,  F3_);  \
    AV[5] = PKD(dx1, F4_,  F5_,  F6_,  F7_);  \
    AV[6] = PKD(dx1, F8_,  F9_,  F10_, F11_); \
    AV[7] = PKD(dx1, F12_, F13_, F14_, F15_); }
#define KROUND(AV, Q0, Q1) { \
    accA = __builtin_amdgcn_mfma_scale_f32_32x32x64_f8f6f4( \
               AV, Q0, accA, 0, 0, 0, 0x7F7F7F7F, 0, 0x79797979); \
    accB = __builtin_amdgcn_mfma_scale_f32_32x32x64_f8f6f4( \
               AV, Q1, accB, 0, 0, 0, 0x7F7F7F7F, 0, 0x79797979); }

    intx8 pA0 = wq[0],   pA1 = wq[64];
    intx8 pB0 = wq[128], pB1 = wq[192];
    float dA0 = drow[0], dA1 = drow[1];
    float dB0 = drow[2], dB1 = drow[3];

    for (int it = 0; it < 10; ++it) {
        const intx8* wn = wq + 256;
        const float eA0 = drow[4 * it + 4], eA1 = drow[4 * it + 5];
        const float eB0 = drow[4 * it + 6], eB1 = drow[4 * it + 7];

        { MKA8(av, dA0, dA1) KROUND(av, pA0, pA1) }
        pA0 = wn[0]; pA1 = wn[64];

        { MKA8(bv, dB0, dB1) KROUND(bv, pB0, pB1) }
        pB0 = wn[128]; pB1 = wn[192];

        wq = wn;
        dA0 = eA0; dA1 = eA1; dB0 = eB0; dB1 = eB1;
    }
    {
        const intx8* wn = wq + 256;
        const float eA0 = drow[44], eA1 = drow[45];
        { MKA8(av, dA0, dA1) KROUND(av, pA0, pA1) }
        pA0 = wn[0]; pA1 = wn[64];
        { MKA8(bv, dB0, dB1) KROUND(bv, pB0, pB1) }
        { MKA8(cv, eA0, eA1) KROUND(cv, pA0, pA1) }
    }
#undef KROUND
#undef MKA8
#undef PKD
#undef XZ

    // ---- dump raw partial to global, no barrier. C/D layout:
    //      col = lane&31 (+32 for B), row el = (rg&3) + 8*(rg>>2) + 4*lh ----
    float* pdst = partials + ((size_t)blockIdx.x * 4 + wave) * 2048;
#pragma unroll
    for (int rg = 0; rg < 16; ++rg) {
        const int el = (rg & 3) + 8 * (rg >> 2) + 4 * lh;
        pdst[el * 64 + m]      = accA[rg];
        pdst[el * 64 + 32 + m] = accB[rg];
    }
}

// ---------------------------------------------------------------------------
// Kernel 2 — tail: sum 4 partials + b1 + ssp -> h1 (LDS) -> layers 2/3 +
// asy + output. W2 staged in LDS (R17, verified); ds_read_b128 2-way = free.
// ---------------------------------------------------------------------------
__global__ __launch_bounds__(BLOCK)
void wfnet_tail(const float* __restrict__ rs,
                const float* __restrict__ coords,
                const float* __restrict__ charges,
                const float* __restrict__ partials,
                const float* __restrict__ b1,
                const float* __restrict__ W2,
                const float* __restrict__ b2,
                const float* __restrict__ W3,
                const float* __restrict__ b3,
                float* __restrict__ out)
{
    __shared__ float lds_rs[TB * N_EL * 3];   // 6 KB
    __shared__ float lds_h1[TB * H1LD];       // 8.7 KB
    __shared__ float lds_w2[HIDDEN * HIDDEN]; // 16 KB

    const int tid = threadIdx.x;
    const int el  = tid >> 3;                // 0..31
    const int g   = tid & 7;
    const int b   = blockIdx.x * TB + el;

    // stage rs for asy
    {
        const float* rs_blk = rs + (size_t)blockIdx.x * (TB * N_EL * 3);
        for (int k = tid; k < TB * N_EL * 3; k += BLOCK) lds_rs[k] = rs_blk[k];
    }
    // stage W2 (4 float4 per thread)
    {
        float4* dst = (float4*)lds_w2;
        const float4* src = (const float4*)W2;
#pragma unroll
        for (int i = 0; i < 4; ++i) dst[tid + 256 * i] = src[tid + 256 * i];
    }

    // sum 4 wave-partials for (el, cols g*8..g*8+7), + b1, ssp -> LDS h1
    {
        const float* pb = partials + (size_t)blockIdx.x * 8192 + el * 64 + g * 8;
        const float4 p00 = ((const float4*)(pb + 0 * 2048))[0];
        const float4 p01 = ((const float4*)(pb + 0 * 2048))[1];
        const float4 p10 = ((const float4*)(pb + 1 * 2048))[0];
        const float4 p11 = ((const float4*)(pb + 1 * 2048))[1];
        const float4 p20 = ((const float4*)(pb + 2 * 2048))[0];
        const float4 p21 = ((const float4*)(pb + 2 * 2048))[1];
        const float4 p30 = ((const float4*)(pb + 3 * 2048))[0];
        const float4 p31 = ((const float4*)(pb + 3 * 2048))[1];
        const float4 ba = ((const float4*)(b1 + g * 8))[0];
        const float4 bb = ((const float4*)(b1 + g * 8))[1];
        float* h1w = lds_h1 + el * H1LD + g * 8;
        h1w[0] = ssp(p00.x + p10.x + p20.x + p30.x + ba.x);
        h1w[1] = ssp(p00.y + p10.y + p20.y + p30.y + ba.y);
        h1w[2] = ssp(p00.z + p10.z + p20.z + p30.z + ba.z);
        h1w[3] = ssp(p00.w + p10.w + p20.w + p30.w + ba.w);
        h1w[4] = ssp(p01.x + p11.x + p21.x + p31.x + bb.x);
        h1w[5] = ssp(p01.y + p11.y + p21.y + p31.y + bb.y);
        h1w[6] = ssp(p01.z + p11.z + p21.z + p31.z + bb.z);
        h1w[7] = ssp(p01.w + p11.w + p21.w + p31.w + bb.w);
    }

    // asy partial: this thread's 8 el-nuc pairs (needs only lds_rs)
    float asy = 0.0f;
    __syncthreads();   // rs + W2 staged AND h1 visible
    {
        const float* myrs = lds_rs + el * (N_EL * 3);
        const float4 ch = *(const float4*)charges;
#pragma unroll
        for (int i = 0; i < 8; ++i) {
            const int p = g + 8 * i;
            const int e = p >> 2, n = p & 3;
            const float dx = myrs[e * 3 + 0] - coords[n * 3 + 0];
            const float dy = myrs[e * 3 + 1] - coords[n * 3 + 1];
            const float dz = myrs[e * 3 + 2] - coords[n * 3 + 2];
            const float d = sqrtf(dx * dx + dy * dy + dz * dz);
            const float Z = (n < 2) ? ((n == 0) ? ch.x : ch.y)
                                    : ((n == 2) ? ch.z : ch.w);
            asy += (Z * d + d * d) / (1.0f + d);   // decay = sqrt(2*0.5) = 1
        }
    }
    asy = redg(asy);

    // layers 2/3 (W2 from LDS)
    const float4* __restrict__ W2v = (const float4*)lds_w2;
    const float4* __restrict__ b2v = (const float4*)b2;
    const int wbi = g * 2;
    const float4 b2a = b2v[wbi], b2b = b2v[wbi + 1];
    float s0 = b2a.x, s1 = b2a.y, s2 = b2a.z, s3 = b2a.w;
    float s4 = b2b.x, s5 = b2b.y, s6 = b2b.z, s7 = b2b.w;

    const float* __restrict__ h1row = lds_h1 + el * H1LD;
    for (int k = 0; k < HIDDEN; ++k) {
        const float hk  = h1row[k];
        const float4 wa = W2v[k * 16 + wbi];
        const float4 wb = W2v[k * 16 + wbi + 1];
        s0 = fmaf(hk, wa.x, s0); s1 = fmaf(hk, wa.y, s1);
        s2 = fmaf(hk, wa.z, s2); s3 = fmaf(hk, wa.w, s3);
        s4 = fmaf(hk, wb.x, s4); s5 = fmaf(hk, wb.y, s5);
        s6 = fmaf(hk, wb.z, s6); s7 = fmaf(hk, wb.w, s7);
    }

    const float4* __restrict__ W3v = (const float4*)W3;
    const float4 w3a = W3v[wbi], w3b = W3v[wbi + 1];
    float part = ssp(s0) * w3a.x + ssp(s1) * w3a.y
               + ssp(s2) * w3a.z + ssp(s3) * w3a.w
               + ssp(s4) * w3b.x + ssp(s5) * w3b.y
               + ssp(s6) * w3b.z + ssp(s7) * w3b.w;
    part = redg(part);

    if (g == 0) {
        const float ys = part + b3[0];
        out[b] = __expf(ys) * __expf(-asy);
    }
}

extern "C" void kernel_launch(void* const* d_in, const int* in_sizes, int n_in,
                              void* d_out, int out_size, void* d_ws, size_t ws_size,
                              hipStream_t stream) {
    const float* rs      = (const float*)d_in[0];
    const float* coords  = (const float*)d_in[1];
    const float* charges = (const float*)d_in[2];
    const float* W1      = (const float*)d_in[3];
    const float* b1      = (const float*)d_in[4];
    const float* W2      = (const float*)d_in[5];
    const float* b2      = (const float*)d_in[6];
    const float* W3      = (const float*)d_in[7];
    const float* b3      = (const float*)d_in[8];
    float* out = (float*)d_out;

    const int batch = in_sizes[0] / (N_EL * 3);   // 32768
    intx8* w1f8     = (intx8*)d_ws;               // 368 KB fp8 W1
    float* partials = (float*)((char*)d_ws + WS_PART_OFF);  // 32 MB

    prep_w1_kernel<<<N_PAIRS / 2, 256, 0, stream>>>(W1, w1f8);
    wfnet_gemm<<<batch / TB, BLOCK, 0, stream>>>(rs, coords, w1f8, partials);
    wfnet_tail<<<batch / TB, BLOCK, 0, stream>>>(rs, coords, charges, partials,
                                                 b1, W2, b2, W3, b3, out);
}